// Round 8
// baseline (223.858 us; speedup 1.0000x reference)
//
#include <hip/hip_runtime.h>

// Depthwise 2x2 Haar high-pass, stride 1, VALID.
// in:  (B=4, C=128, H=512, W=512) fp32 -> out: (B, C, 511, 511) fp32
// out[y,x] = 0.5*((in[y,x]-in[y,x+1]) - (in[y+1,x]-in[y+1,x+1]))
//
// Round 8: persistent half-channel blocks (halo -> L1 hits) + 4 blocks/CU.
//  - 1024 blocks x 256 thr; block owns half a channel (256 output rows),
//    processed as 16 sequential groups of 16 rows. Group-boundary rows are
//    re-read by the SAME block (same CU, adjacent in time) -> L1/L2 hit,
//    no cross-XCD HBM halo (round 7 paid +3.1% fetch for this).
//  - LDS 32 KB -> 4 blocks/CU: finer read/write phase interleave per CU.
//  - Phase B: round-7's proven 16B-aligned NT dwordx4 span streaming.

#define Bn 4
#define Cn 128
#define Hn 512
#define Wn 512
#define OH 511
#define OW 511
#define GR 16          // output rows per group
#define NG 16          // groups per block (GR*NG = 256 rows = half channel)
#define TPB 256

typedef float f4 __attribute__((ext_vector_type(4)));

__global__ __launch_bounds__(TPB)
void haar_kernel(const float* __restrict__ in, float* __restrict__ out) {
    __shared__ float lds[GR * 512];   // 32 KB

    const int bx   = blockIdx.x;      // 0..1023
    const int ch   = bx >> 1;         // 0..511 (b*C + c)
    const int half = bx & 1;
    const int yb   = half * 256;      // half-channel base output row
    const int t    = threadIdx.x;
    const int h    = t >> 7;          // half 0/1 -> 8 output rows each
    const int u    = t & 127;
    const int c0   = u * 4;           // 4 contiguous cols per thread

    const float* __restrict__ inCh = in + (size_t)ch * Hn * Wn;
    const int ecol = (u == 127) ? (c0 + 3) : (c0 + 4);  // col 512 absent; unused there

    for (int g = 0; g < NG; ++g) {
        const int y0 = yb + g * GR;

        // ---- Phase A: compute 16 output rows into LDS ----
        // half h: output rows y0+8h .. y0+8h+7 (input rows y0+8h .. y0+8h+8)
        f4 R[9]; float E[9];
#pragma unroll
        for (int i = 0; i < 9; ++i) {
            int ys = y0 + 8 * h + i;
            if (ys > Hn - 1) ys = Hn - 1;               // tail clamp (last group only)
            const float* p = inCh + (size_t)ys * Wn;
            R[i] = *reinterpret_cast<const f4*>(p + c0);
            E[i] = p[ecol];
        }
#pragma unroll
        for (int i = 0; i < 8; ++i) {
            f4 o;
            o.x = 0.5f * ((R[i].x - R[i].y) - (R[i + 1].x - R[i + 1].y));
            o.y = 0.5f * ((R[i].y - R[i].z) - (R[i + 1].y - R[i + 1].z));
            o.z = 0.5f * ((R[i].z - R[i].w) - (R[i + 1].z - R[i + 1].w));
            o.w = 0.5f * ((R[i].w - E[i])   - (R[i + 1].w - E[i + 1]));
            *reinterpret_cast<f4*>(&lds[(8 * h + i) * 512 + c0]) = o;
        }
        __syncthreads();

        // ---- Phase B: stream the contiguous span with aligned NT dwordx4 ----
        const int spanRows = (OH - y0 < GR) ? (OH - y0) : GR;   // 16 (15 for last group)
        const int nspan = spanRows * OW;
        const unsigned F = (unsigned)ch * 261121u + (unsigned)y0 * 511u;  // flat dword base
        float* __restrict__ outSpan = out + F;
        const int s0 = (4 - (int)(F & 3u)) & 3;                  // head dwords to align quads

        if (t < s0 && t < nspan)
            __builtin_nontemporal_store(lds[t], outSpan + t);    // j<3 -> row 0

        const int qn = (nspan - s0) >> 2;                        // aligned quads (~2043)
#pragma unroll
        for (int k = 0; k < 8; ++k) {
            const int q = t + TPB * k;
            if (q < qn) {
                const int j0 = s0 + 4 * q;
                f4 v;
#pragma unroll
                for (int m = 0; m < 4; ++m) {
                    const unsigned jj = (unsigned)(j0 + m);
                    v[m] = lds[jj + jj / 511u];
                }
                __builtin_nontemporal_store(v, reinterpret_cast<f4*>(outSpan + j0));
            }
        }

        const int tl0 = s0 + 4 * qn;
        const int tail = nspan - tl0;
        if (t < tail) {
            const unsigned jj = (unsigned)(tl0 + t);
            __builtin_nontemporal_store(lds[jj + jj / 511u], outSpan + jj);
        }

        __syncthreads();   // protect LDS before next group's phase A overwrites
    }
}

extern "C" void kernel_launch(void* const* d_in, const int* in_sizes, int n_in,
                              void* d_out, int out_size, void* d_ws, size_t ws_size,
                              hipStream_t stream) {
    const float* x = (const float*)d_in[0];
    float* out = (float*)d_out;

    dim3 grid(Bn * Cn * 2);   // 1024 persistent half-channel blocks = 4 blocks/CU
    dim3 block(TPB);
    haar_kernel<<<grid, block, 0, stream>>>(x, out);
}

// Round 9
// 196.162 us; speedup vs baseline: 1.1412x; 1.1412x over previous
//
#include <hip/hip_runtime.h>

// Depthwise 2x2 Haar high-pass, stride 1, VALID.
// in:  (B=4, C=128, H=512, W=512) fp32 -> out: (B, C, 511, 511) fp32
// out[y,x] = 0.5*((in[y,x]-in[y,x+1]) - (in[y+1,x]-in[y+1,x+1]))
//
// Round 9 = round 7 (best, 192.5us) with phase B rebuilt around conflict-free
// vector LDS reads:
//  - per output row, each lane does ds_read_b128 of an ALIGNED LDS quad
//    (contiguous 1KB/wave-instr -> conflict-free), instead of 4 scalar
//    ds_read_b32 at lane-stride-4 (8-way bank conflict, ~2.94x, on the
//    store-dependent critical path of round 7).
//  - global quad grid is offset by hr = (4-(Fr&3))&3 per row; the output quad
//    [hr+4q .. hr+4q+3] = window over LDS quads q,q+1 -> built with 1-lane
//    __shfl_down (hr is wave-uniform -> uniform switch, no scratch).
//  - row-junction orphans: tail(r)+head(r+1) is always exactly one ALIGNED
//    quad (4 dwords) -> lane 0 assembles it from 4 scalar LDS reads.
//  - stores: unchanged round-7 policy (16B-aligned NT dwordx4, dense).

#define Bn 4
#define Cn 128
#define Hn 512
#define Wn 512
#define OH 511
#define OW 511
#define GR 32          // output rows per group
#define TPB 512

typedef float f4 __attribute__((ext_vector_type(4)));

__global__ __launch_bounds__(TPB)
void haar_kernel(const float* __restrict__ in, float* __restrict__ out) {
    __shared__ float lds[GR * 512];   // 64 KB, row stride 512 (col 511 = pad)

    const int g  = blockIdx.x;        // 0..15 row group
    const int ch = blockIdx.y;        // 0..511 (b*C + c)
    const int y0 = g * GR;
    const int t  = threadIdx.x;
    const int h  = t >> 7;            // quarter 0..3 -> 8 output rows each
    const int u  = t & 127;
    const int c0 = u * 4;             // 4 contiguous cols per thread

    const float* __restrict__ inCh = in + (size_t)ch * Hn * Wn;

    // ---- Phase A: compute 32 output rows into LDS (identical to round 7) ----
    f4 R[9]; float E[9];
    const int ecol = (u == 127) ? (c0 + 3) : (c0 + 4);   // col 512 absent; unused there
#pragma unroll
    for (int i = 0; i < 9; ++i) {
        int ys = y0 + 8 * h + i;
        if (ys > Hn - 1) ys = Hn - 1;                    // tail clamp (last group only)
        const float* p = inCh + (size_t)ys * Wn;
        R[i] = *reinterpret_cast<const f4*>(p + c0);
        E[i] = p[ecol];
    }
#pragma unroll
    for (int i = 0; i < 8; ++i) {
        f4 o;
        o.x = 0.5f * ((R[i].x - R[i].y) - (R[i + 1].x - R[i + 1].y));
        o.y = 0.5f * ((R[i].y - R[i].z) - (R[i + 1].y - R[i + 1].z));
        o.z = 0.5f * ((R[i].z - R[i].w) - (R[i + 1].z - R[i + 1].w));
        o.w = 0.5f * ((R[i].w - E[i])   - (R[i + 1].w - E[i + 1]));
        *reinterpret_cast<f4*>(&lds[(8 * h + i) * 512 + c0]) = o;
    }
    __syncthreads();

    // ---- Phase B: per-row streaming, aligned b128 LDS reads + aligned NT stores ----
    const int spanRows = (OH - y0 < GR) ? (OH - y0) : GR;   // 32 (31 for last group)
    const unsigned F = (unsigned)ch * 261121u + (unsigned)y0 * 511u;  // flat dword base
    float* __restrict__ outSpan = out + F;
    const int w = t >> 6, l = t & 63;                        // 8 waves, 4 rows each

#pragma unroll
    for (int m = 0; m < 4; ++m) {
        const int r = w + 8 * m;                             // wave-uniform
        if (r >= spanRows) continue;                         // last group only
        const unsigned Fr = F + 511u * (unsigned)r;
        const int hr = (int)((4u - (Fr & 3u)) & 3u);         // first aligned output col
        float* __restrict__ rowOut = outSpan + 511 * r;
        const float* __restrict__ rowL = &lds[r << 9];

        // Aligned, contiguous, conflict-free LDS quad reads.
        f4 dA = *reinterpret_cast<const f4*>(rowL + 4 * l);         // quad l    (cols 4l..4l+3)
        f4 dB = *reinterpret_cast<const f4*>(rowL + 4 * (l + 64));  // quad l+64

        // First dwords of the NEXT quad, for the window shift.
        float nAx = __shfl_down(dA.x, 1);
        float nAy = __shfl_down(dA.y, 1);
        float nAz = __shfl_down(dA.z, 1);
        const float pBx = __shfl(dB.x, 0);   // quad 64 (lane63's next quad)
        const float pBy = __shfl(dB.y, 0);
        const float pBz = __shfl(dB.z, 0);
        if (l == 63) { nAx = pBx; nAy = pBy; nAz = pBz; }
        const float nBx = __shfl_down(dB.x, 1);
        const float nBy = __shfl_down(dB.y, 1);
        const float nBz = __shfl_down(dB.z, 1);   // lane63's values unused

        f4 vA, vB;
        switch (hr) {   // wave-uniform
        case 0:
            vA = dA; vB = dB; break;
        case 1:
            vA.x = dA.y; vA.y = dA.z; vA.z = dA.w; vA.w = nAx;
            vB.x = dB.y; vB.y = dB.z; vB.z = dB.w; vB.w = nBx; break;
        case 2:
            vA.x = dA.z; vA.y = dA.w; vA.z = nAx; vA.w = nAy;
            vB.x = dB.z; vB.y = dB.w; vB.z = nBx; vB.w = nBy; break;
        default:
            vA.x = dA.w; vA.y = nAx; vA.z = nAy; vA.w = nAz;
            vB.x = dB.w; vB.y = nBx; vB.z = nBy; vB.w = nBz; break;
        }

        // Output quads: q_out = l (cols hr+4l..) and q_out = 64+l (l<63); 127 total.
        __builtin_nontemporal_store(vA, reinterpret_cast<f4*>(rowOut + hr + 4 * l));
        if (l < 63)
            __builtin_nontemporal_store(vB, reinterpret_cast<f4*>(rowOut + hr + 4 * (l + 64)));

        // Junction quad r -> r+1: orphan cols 508+hr..510 of r + 0..hr of r+1 (always 4 dwords).
        if (hr != 3 && l == 0) {
            const int s = 508 + hr;
            if (r + 1 < spanRows) {
                const float* rowL2 = &lds[(r + 1) << 9];
                f4 jv;
#pragma unroll
                for (int mm = 0; mm < 4; ++mm) {
                    const int col = s + mm;
                    jv[mm] = (col <= 510) ? rowL[col] : rowL2[col - 511];
                }
                __builtin_nontemporal_store(jv, reinterpret_cast<f4*>(rowOut + s));
            } else {
                // span tail (last row): scalar cols s..510
                for (int col = s; col <= 510; ++col)
                    __builtin_nontemporal_store(rowL[col], rowOut + col);
            }
        }
        // Span head: row 0 cols 0..hr-1 (misaligned start of the span).
        if (r == 0 && l < hr)
            __builtin_nontemporal_store(rowL[l], rowOut + l);
    }
}

extern "C" void kernel_launch(void* const* d_in, const int* in_sizes, int n_in,
                              void* d_out, int out_size, void* d_ws, size_t ws_size,
                              hipStream_t stream) {
    const float* x = (const float*)d_in[0];
    float* out = (float*)d_out;

    dim3 grid(Hn / GR, Bn * Cn);   // (16, 512) = 8192 blocks (turnover pipelining)
    dim3 block(TPB);
    haar_kernel<<<grid, block, 0, stream>>>(x, out);
}

// Round 10
// 192.379 us; speedup vs baseline: 1.1636x; 1.0197x over previous
//
#include <hip/hip_runtime.h>

// Depthwise 2x2 Haar high-pass, stride 1, VALID.
// in:  (B=4, C=128, H=512, W=512) fp32 -> out: (B, C, 511, 511) fp32
// out[y,x] = 0.5*((in[y,x]-in[y,x+1]) - (in[y+1,x]-in[y+1,x+1]))
//
// FINAL (= round 7, best at 192.5us = 90% of the 6.29 TB/s copy ceiling).
// Structure: LDS-staged dense output streaming.
//  - Phase A: 32 output rows computed into LDS [32][512] (vector global
//    loads, ds_write_b128 conflict-free).
//  - Phase B: the group's output is a CONTIGUOUS 32*511-dword span; streamed
//    with 16B-ALIGNED nontemporal dwordx4 stores (head/tail scalars fix the
//    per-channel span-start phase F%4 == ch%4). Dense fully-covered 64B
//    lines -> no partial-line write amplification (round-5 counters showed
//    1.77x WRITE_SIZE for strided row stores; this fixed it, 256->208->192us).
//  - LDS quad reads are 4x ds_read_b32 at lane-stride-4 (8-way bank alias);
//    round 9 proved this is fully hidden under the HBM stream (conflict-free
//    b128 variant: 196us, no gain).
//  - NT stores: write stream has zero reuse; avoids evicting the harness's
//    dirty 0xAA L3 fill on the critical path.
// Exonerated non-bottlenecks (all within noise or regressions):
//    store alignment alone (r2), depth-1 prefetch (r3), 8-row ping-pong +
//    NT (r4), few-deep-streams geometry (r5, 374us), persistent blocks +
//    halo elimination (r8, 224us), conflict-free LDS reads (r9).

#define Bn 4
#define Cn 128
#define Hn 512
#define Wn 512
#define OH 511
#define OW 511
#define GR 32          // output rows per group
#define TPB 512

typedef float f4 __attribute__((ext_vector_type(4)));

__global__ __launch_bounds__(TPB)
void haar_kernel(const float* __restrict__ in, float* __restrict__ out) {
    __shared__ float lds[GR * 512];   // 64 KB

    const int g  = blockIdx.x;        // 0..15 row group
    const int ch = blockIdx.y;        // 0..511 (b*C + c)
    const int y0 = g * GR;
    const int t  = threadIdx.x;
    const int h  = t >> 7;            // quarter 0..3 -> 8 output rows each
    const int u  = t & 127;
    const int c0 = u * 4;             // 4 contiguous cols per thread

    const float* __restrict__ inCh = in + (size_t)ch * Hn * Wn;

    // ---- Phase A: compute 32 output rows into LDS ----
    // quarter h: output rows y0+8h .. y0+8h+7 (input rows y0+8h .. y0+8h+8)
    f4 R[9]; float E[9];
    const int ecol = (u == 127) ? (c0 + 3) : (c0 + 4);   // col 512 absent; value unused there
#pragma unroll
    for (int i = 0; i < 9; ++i) {
        int ys = y0 + 8 * h + i;
        if (ys > Hn - 1) ys = Hn - 1;                    // tail clamp (last group only)
        const float* p = inCh + (size_t)ys * Wn;
        R[i] = *reinterpret_cast<const f4*>(p + c0);
        E[i] = p[ecol];
    }
#pragma unroll
    for (int i = 0; i < 8; ++i) {
        f4 o;
        o.x = 0.5f * ((R[i].x - R[i].y) - (R[i + 1].x - R[i + 1].y));
        o.y = 0.5f * ((R[i].y - R[i].z) - (R[i + 1].y - R[i + 1].z));
        o.z = 0.5f * ((R[i].z - R[i].w) - (R[i + 1].z - R[i + 1].w));
        o.w = 0.5f * ((R[i].w - E[i])   - (R[i + 1].w - E[i + 1]));
        *reinterpret_cast<f4*>(&lds[(8 * h + i) * 512 + c0]) = o;
    }
    __syncthreads();

    // ---- Phase B: stream the contiguous span with aligned NT dwordx4 ----
    const int spanRows = (OH - y0 < GR) ? (OH - y0) : GR;   // 32 (31 for last group)
    const int nspan = spanRows * OW;                         // dwords in span
    const unsigned F = (unsigned)ch * 261121u + (unsigned)y0 * 511u;  // flat dword base
    float* __restrict__ outSpan = out + F;
    const int s0 = (4 - (int)(F & 3u)) & 3;                  // head dwords to align quads

    // head (<=3 dwords)
    if (t < s0 && t < nspan)
        __builtin_nontemporal_store(lds[t], outSpan + t);    // j<3 -> row 0, lds[j]

    const int qn = (nspan - s0) >> 2;                        // aligned quads
#pragma unroll
    for (int k = 0; k < 8; ++k) {
        const int q = t + TPB * k;
        if (q < qn) {
            const int j0 = s0 + 4 * q;
            f4 v;
#pragma unroll
            for (int m = 0; m < 4; ++m) {
                const unsigned jj = (unsigned)(j0 + m);
                v[m] = lds[jj + jj / 511u];
            }
            __builtin_nontemporal_store(v, reinterpret_cast<f4*>(outSpan + j0));
        }
    }

    // tail (<=3 dwords)
    const int tl0 = s0 + 4 * qn;
    const int tail = nspan - tl0;
    if (t < tail) {
        const unsigned jj = (unsigned)(tl0 + t);
        __builtin_nontemporal_store(lds[jj + jj / 511u], outSpan + jj);
    }
}

extern "C" void kernel_launch(void* const* d_in, const int* in_sizes, int n_in,
                              void* d_out, int out_size, void* d_ws, size_t ws_size,
                              hipStream_t stream) {
    const float* x = (const float*)d_in[0];
    float* out = (float*)d_out;

    dim3 grid(Hn / GR, Bn * Cn);   // (16, 512)
    dim3 block(TPB);
    haar_kernel<<<grid, block, 0, stream>>>(x, out);
}